// Round 8
// baseline (399.633 us; speedup 1.0000x reference)
//
#include <hip/hip_runtime.h>

#define HIDDEN 128
#define NB_SHIFT 7            // 128 dst nodes per bucket
#define NPB 128               // nodes per bucket
#define EPB 4096              // edges per partition/hist block

typedef __attribute__((ext_vector_type(8))) short short8;
typedef __attribute__((ext_vector_type(4))) float f32x4;
typedef _Float16 f16;
typedef __attribute__((ext_vector_type(8))) _Float16 f16x8;

// float -> bf16 (RNE), and back
__device__ __forceinline__ ushort f2bf(float a) {
  union { float f; unsigned u; } c; c.f = a;
  return (ushort)((c.u + 0x7FFFu + ((c.u >> 16) & 1u)) >> 16);
}
__device__ __forceinline__ float bf2f(ushort h) {
  union { unsigned u; float f; } c; c.u = ((unsigned)h) << 16;
  return c.f;
}

// ---------------------------------------------------------------------------
// CSR build A: per-bucket edge histogram (LDS-local, then merge).
// ---------------------------------------------------------------------------
__global__ __launch_bounds__(256) void bucket_hist_kernel(
    const int* __restrict__ dst, int* __restrict__ bcnt, int E, int NB) {
  __shared__ int loc[512];
  const int t = threadIdx.x;
  loc[t] = 0; loc[t + 256] = 0;
  __syncthreads();
  const int base = blockIdx.x * EPB;
  const int end = min(base + EPB, E);
  for (int e = base + t; e < end; e += 256)
    atomicAdd(&loc[dst[e] >> NB_SHIFT], 1);
  __syncthreads();
  for (int b = t; b < NB; b += 256)
    if (loc[b]) atomicAdd(&bcnt[b], loc[b]);
}

// ---------------------------------------------------------------------------
// CSR build B: exclusive scan of <=512 bucket counts -> pairOff + gCursor.
// ---------------------------------------------------------------------------
__global__ __launch_bounds__(256) void scan_buckets_kernel(
    const int* __restrict__ bcnt, int* __restrict__ pairOff,
    int* __restrict__ gCursor, int NB) {
  __shared__ int sh[512];
  const int t = threadIdx.x;
  const int v0 = (t < NB) ? bcnt[t] : 0;
  const int v1 = (t + 256 < NB) ? bcnt[t + 256] : 0;
  sh[t] = v0; sh[t + 256] = v1;
  __syncthreads();
#pragma unroll
  for (int off = 1; off < 512; off <<= 1) {
    int a = (t >= off) ? sh[t - off] : 0;
    int b = (t + 256 >= off) ? sh[t + 256 - off] : 0;
    __syncthreads();
    sh[t] += a; sh[t + 256] += b;
    __syncthreads();
  }
  const int e0 = sh[t] - v0;        // exclusive
  const int e1 = sh[t + 256] - v1;
  pairOff[t] = e0; gCursor[t] = e0;
  pairOff[t + 256] = e1; gCursor[t + 256] = e1;
  if (t == 255) pairOff[512] = sh[511];
}

// ---------------------------------------------------------------------------
// CSR build C: partition edges into bucket-contiguous PACKED pairs:
//   p = (dst & 127) << 25 | src      (src < 2^25)
// ---------------------------------------------------------------------------
__global__ __launch_bounds__(256) void partition_kernel(
    const int* __restrict__ src, const int* __restrict__ dst,
    int* __restrict__ gCursor, int* __restrict__ pairs, int E, int NB) {
  __shared__ int loc[512];
  __shared__ int cur[512];
  const int t = threadIdx.x;
  loc[t] = 0; loc[t + 256] = 0;
  __syncthreads();
  const int base = blockIdx.x * EPB;
  const int end = min(base + EPB, E);
  for (int e = base + t; e < end; e += 256)
    atomicAdd(&loc[dst[e] >> NB_SHIFT], 1);
  __syncthreads();
  for (int b = t; b < NB; b += 256)
    cur[b] = loc[b] ? atomicAdd(&gCursor[b], loc[b]) : 0;
  __syncthreads();
  for (int e = base + t; e < end; e += 256) {
    const int d = dst[e];
    const int p = atomicAdd(&cur[d >> NB_SHIFT], 1);
    pairs[p] = ((d & (NPB - 1)) << 25) | src[e];
  }
}

// ---------------------------------------------------------------------------
// CSR build D: one block per bucket -> rowptr + col (dense, L2-resident).
// ---------------------------------------------------------------------------
__global__ __launch_bounds__(256) void build_csr_kernel(
    const int* __restrict__ pairs, const int* __restrict__ pairOff,
    int* __restrict__ rowptr, int* __restrict__ col, int M, int E, int NB) {
  __shared__ int deg[NPB];
  __shared__ int pre[NPB];
  __shared__ int cur[NPB];
  const int b = blockIdx.x;
  const int t = threadIdx.x;
  const int s = pairOff[b];
  const int e2 = pairOff[b + 1];
  const int nodeBase = b << NB_SHIFT;
  const int nNodes = min(NPB, M - nodeBase);
  if (t < NPB) deg[t] = 0;
  __syncthreads();
  for (int i = s + t; i < e2; i += 256)
    atomicAdd(&deg[((unsigned)pairs[i]) >> 25], 1);
  __syncthreads();
  if (t < NPB) pre[t] = deg[t];
  __syncthreads();
#pragma unroll
  for (int off = 1; off < NPB; off <<= 1) {
    int v = (t < NPB && t >= off) ? pre[t - off] : 0;
    __syncthreads();
    if (t < NPB) pre[t] += v;
    __syncthreads();
  }
  if (t < nNodes) rowptr[nodeBase + t] = s + pre[t] - deg[t];
  if (b == NB - 1 && t == 0) rowptr[M] = E;
  if (t < NPB) cur[t] = pre[t] - deg[t];
  __syncthreads();
  for (int i = s + t; i < e2; i += 256) {
    const int pr = pairs[i];
    const int pos = s + atomicAdd(&cur[((unsigned)pr) >> 25], 1);
    col[pos] = pr & 0x1FFFFFF;
  }
}

// ---------------------------------------------------------------------------
// Degree counting-sort (3 kernels): histogram of clamped degree (256 bins),
// DESCENDING exclusive scan, scatter node ids -> perm. Waves then own 16
// near-equal-degree nodes (kills the max-vs-mean divergence tax in the
// fused gather); descending order = LPT block scheduling (heavy blocks
// launch first, no tail straggler). Per-node edge order unchanged ->
// identical arithmetic.
// ---------------------------------------------------------------------------
__global__ __launch_bounds__(256) void deg_hist_kernel(
    const int* __restrict__ rowptr, int* __restrict__ dhist, int M) {
  __shared__ int loc[256];
  const int t = threadIdx.x;
  loc[t] = 0;
  __syncthreads();
  const int n = blockIdx.x * 256 + t;
  if (n < M) {
    int d = rowptr[n + 1] - rowptr[n];
    atomicAdd(&loc[min(d, 255)], 1);
  }
  __syncthreads();
  if (loc[t]) atomicAdd(&dhist[t], loc[t]);
}

__global__ __launch_bounds__(256) void deg_scan_kernel(
    const int* __restrict__ dhist, int* __restrict__ dcur) {
  __shared__ int sh[256];
  const int t = threadIdx.x;
  const int v = dhist[255 - t];  // reversed: descending degree order
  sh[t] = v;
  __syncthreads();
#pragma unroll
  for (int off = 1; off < 256; off <<= 1) {
    int a = (t >= off) ? sh[t - off] : 0;
    __syncthreads();
    sh[t] += a;
    __syncthreads();
  }
  dcur[255 - t] = sh[t] - v;  // exclusive prefix over larger degrees
}

__global__ __launch_bounds__(256) void deg_scatter_kernel(
    const int* __restrict__ rowptr, int* __restrict__ dcur,
    int* __restrict__ perm, int M) {
  const int n = blockIdx.x * 256 + threadIdx.x;
  if (n >= M) return;
  const int d = min(rowptr[n + 1] - rowptr[n], 255);
  const int pos = atomicAdd(&dcur[d], 1);
  perm[pos] = n;
}

// ---------------------------------------------------------------------------
// fp32 -> fp16 feature convert (8 elems/thread)
// ---------------------------------------------------------------------------
__global__ __launch_bounds__(256) void f2h_kernel(const float* __restrict__ in,
                                                  f16* __restrict__ out, int n8) {
  int i = blockIdx.x * 256 + threadIdx.x;
  if (i >= n8) return;
  const float4* p = (const float4*)(in + (size_t)i * 8);
  float4 a = p[0], b = p[1];
  f16x8 o;
  o[0] = (f16)a.x; o[1] = (f16)a.y; o[2] = (f16)a.z; o[3] = (f16)a.w;
  o[4] = (f16)b.x; o[5] = (f16)b.y; o[6] = (f16)b.z; o[7] = (f16)b.w;
  *(f16x8*)(out + (size_t)i * 8) = o;
}

// ---------------------------------------------------------------------------
// Prepack weights into MFMA B-fragment-linear bf16 hi/lo planes.
//   frag (ks, nf), lane, j  ->  k = ks*32 + (lane>>4)*8 + j, n = nf*16 + (lane&15)
// ---------------------------------------------------------------------------
__global__ __launch_bounds__(256) void prepack_kernel(
    const float* __restrict__ Wa, const float* __restrict__ Wb,
    const float* __restrict__ Wc, const float* __restrict__ Wd,
    ushort* __restrict__ out) {
  int idx = blockIdx.x * 256 + threadIdx.x;  // 0..8191
  int w = idx >> 11;
  int rem = idx & 2047;
  int ks = rem >> 9;
  int nf = (rem >> 6) & 7;
  int lane = rem & 63;
  const float* W = (w == 0) ? Wa : (w == 1) ? Wb : (w == 2) ? Wc : Wd;
  const int kbase = ks * 32 + (lane >> 4) * 8;
  const int n = nf * 16 + (lane & 15);
  ushort* oh = out + (size_t)w * 32768 + (size_t)rem * 8;
  ushort* ol = oh + 16384;
#pragma unroll
  for (int j = 0; j < 8; ++j) {
    float v = W[(size_t)(kbase + j) * HIDDEN + n];
    ushort h = f2bf(v);
    oh[j] = h;
    ol[j] = f2bf(v - bf2f(h));
  }
}

// ---------------------------------------------------------------------------
// FUSED GIN layer (R5 structure + degree-sorted perm + stride-133 LDS).
// Block = 64 nodes, 4 waves x 16 nodes. Lane (r,g) owns node PERM[mBase+r]'s
// dims {ks*32+g*8..+8} == the MFMA A-fragment decomposition, so gather
// accumulators feed GEMM1 from registers (no global intermediate).
// Divergent per-lane edge loop, but perm makes the 16 degrees per wave
// near-equal -> trip count effectively uniform (R7's cooperative variant
// serialized nodes and regressed; reverted). h1 stride 133 (bank step 5,
// invertible mod 32): GEMM2 b128 A-reads + bias writes = 2-way (free) vs
// 8-/4-way at 132. Zero __syncthreads (wave-private h1 tile).
// LDS 34 KB -> 4 blocks/CU; launch_bounds(256,4) caps at 128 VGPR.
// ---------------------------------------------------------------------------
__global__ __launch_bounds__(256, 4) void gin_layer_kernel(
    const f16* __restrict__ xh, const int* __restrict__ rowptr,
    const int* __restrict__ col, const int* __restrict__ perm,
    const ushort* __restrict__ W1p, const float* __restrict__ b1,
    const ushort* __restrict__ W2p, const float* __restrict__ b2,
    f16* __restrict__ Ch, const float* __restrict__ Wr,
    const float* __restrict__ br, float* __restrict__ outv, int M,
    int doReadout) {
  __shared__ float h1[4][16][133];
  const int t = threadIdx.x;
  const int lane = t & 63;
  const int w = t >> 6;
  const int r = lane & 15;     // node row within wave / D col index
  const int g = lane >> 4;     // k-group / D row group
  const int mBase = blockIdx.x * 64 + w * 16;
  int lrow = mBase + r;
  if (lrow > M - 1) lrow = M - 1;  // clamp: garbage only affects rows >= M
  const int arow = perm[lrow];     // physical node id

  // ---- fused aggregation: a32[ks][j] = xh[arow] + sum_e xh[col[e]]
  float a32[4][8];
  {
    const f16* rp = xh + (size_t)arow * HIDDEN + g * 8;
    f16x8 s0 = *(const f16x8*)(rp);
    f16x8 s1 = *(const f16x8*)(rp + 32);
    f16x8 s2 = *(const f16x8*)(rp + 64);
    f16x8 s3 = *(const f16x8*)(rp + 96);
#pragma unroll
    for (int j = 0; j < 8; ++j) {
      a32[0][j] = (float)s0[j]; a32[1][j] = (float)s1[j];
      a32[2][j] = (float)s2[j]; a32[3][j] = (float)s3[j];
    }
    const int s = rowptr[arow];
    const int e = rowptr[arow + 1];
    int i = s;
    for (; i + 1 < e; i += 2) {
      const int c0 = col[i], c1 = col[i + 1];
      const f16* p0 = xh + (size_t)c0 * HIDDEN + g * 8;
      const f16* p1 = xh + (size_t)c1 * HIDDEN + g * 8;
      f16x8 u0 = *(const f16x8*)(p0);
      f16x8 u1 = *(const f16x8*)(p0 + 32);
      f16x8 u2 = *(const f16x8*)(p0 + 64);
      f16x8 u3 = *(const f16x8*)(p0 + 96);
      f16x8 v0 = *(const f16x8*)(p1);
      f16x8 v1 = *(const f16x8*)(p1 + 32);
      f16x8 v2 = *(const f16x8*)(p1 + 64);
      f16x8 v3 = *(const f16x8*)(p1 + 96);
#pragma unroll
      for (int j = 0; j < 8; ++j) {
        a32[0][j] += (float)u0[j] + (float)v0[j];
        a32[1][j] += (float)u1[j] + (float)v1[j];
        a32[2][j] += (float)u2[j] + (float)v2[j];
        a32[3][j] += (float)u3[j] + (float)v3[j];
      }
    }
    if (i < e) {
      const int c0 = col[i];
      const f16* p0 = xh + (size_t)c0 * HIDDEN + g * 8;
      f16x8 u0 = *(const f16x8*)(p0);
      f16x8 u1 = *(const f16x8*)(p0 + 32);
      f16x8 u2 = *(const f16x8*)(p0 + 64);
      f16x8 u3 = *(const f16x8*)(p0 + 96);
#pragma unroll
      for (int j = 0; j < 8; ++j) {
        a32[0][j] += (float)u0[j];
        a32[1][j] += (float)u1[j];
        a32[2][j] += (float)u2[j];
        a32[3][j] += (float)u3[j];
      }
    }
  }

  f32x4 acc[8];
#pragma unroll
  for (int i = 0; i < 8; ++i) acc[i] = (f32x4){0.f, 0.f, 0.f, 0.f};

  // ---- GEMM1: acc[nf] += a32(16x128) @ W1[:, nf*16..]
#pragma unroll
  for (int ks = 0; ks < 4; ++ks) {
    short8 ah, al;
#pragma unroll
    for (int j = 0; j < 8; ++j) {
      ushort h = f2bf(a32[ks][j]);
      ah[j] = (short)h;
      al[j] = (short)f2bf(a32[ks][j] - bf2f(h));
    }
#pragma unroll
    for (int nf = 0; nf < 8; ++nf) {
      const ushort* bp = W1p + ((size_t)(ks * 8 + nf) * 64 + lane) * 8;
      short8 bh = *(const short8*)bp;
      short8 bl = *(const short8*)(bp + 16384);
      acc[nf] = __builtin_amdgcn_mfma_f32_16x16x32_bf16(ah, bh, acc[nf], 0, 0, 0);
      acc[nf] = __builtin_amdgcn_mfma_f32_16x16x32_bf16(al, bh, acc[nf], 0, 0, 0);
      acc[nf] = __builtin_amdgcn_mfma_f32_16x16x32_bf16(ah, bl, acc[nf], 0, 0, 0);
    }
  }

  // ---- bias + relu, park h1 in wave-private LDS (row=4g+q, col=nf*16+r)
#pragma unroll
  for (int nf = 0; nf < 8; ++nf) {
    float bv = b1[nf * 16 + r];
#pragma unroll
    for (int q = 0; q < 4; ++q)
      h1[w][g * 4 + q][nf * 16 + r] = fmaxf(acc[nf][q] + bv, 0.f);
    acc[nf] = (f32x4){0.f, 0.f, 0.f, 0.f};
  }

  // ---- GEMM2: acc[nf] += h1(16x128) @ W2[:, nf*16..] (A-frags from LDS)
#pragma unroll
  for (int ks = 0; ks < 4; ++ks) {
    const float* hp = &h1[w][r][ks * 32 + g * 8];
    float4 a0 = *(const float4*)hp;
    float4 a1 = *(const float4*)(hp + 4);
    float av[8] = {a0.x, a0.y, a0.z, a0.w, a1.x, a1.y, a1.z, a1.w};
    short8 ah, al;
#pragma unroll
    for (int j = 0; j < 8; ++j) {
      ushort h = f2bf(av[j]);
      ah[j] = (short)h;
      al[j] = (short)f2bf(av[j] - bf2f(h));
    }
#pragma unroll
    for (int nf = 0; nf < 8; ++nf) {
      const ushort* bp = W2p + ((size_t)(ks * 8 + nf) * 64 + lane) * 8;
      short8 bh = *(const short8*)bp;
      short8 bl = *(const short8*)(bp + 16384);
      acc[nf] = __builtin_amdgcn_mfma_f32_16x16x32_bf16(ah, bh, acc[nf], 0, 0, 0);
      acc[nf] = __builtin_amdgcn_mfma_f32_16x16x32_bf16(al, bh, acc[nf], 0, 0, 0);
      acc[nf] = __builtin_amdgcn_mfma_f32_16x16x32_bf16(ah, bl, acc[nf], 0, 0, 0);
    }
  }

  if (!doReadout) {
    // bias + relu -> LDS, then coalesced fp16 stores (row = perm[gm])
#pragma unroll
    for (int nf = 0; nf < 8; ++nf) {
      float bv = b2[nf * 16 + r];
#pragma unroll
      for (int q = 0; q < 4; ++q)
        h1[w][g * 4 + q][nf * 16 + r] = fmaxf(acc[nf][q] + bv, 0.f);
    }
    const int rr = lane >> 2;          // 0..15
    const int c0 = (lane & 3) * 32;    // 0,32,64,96
    const int gm = mBase + rr;
    if (gm < M) {
      const int orow = perm[gm];
#pragma unroll
      for (int i = 0; i < 4; ++i) {
        float4 v0 = *(const float4*)&h1[w][rr][c0 + i * 8];
        float4 v1 = *(const float4*)&h1[w][rr][c0 + i * 8 + 4];
        f16x8 o;
        o[0] = (f16)v0.x; o[1] = (f16)v0.y; o[2] = (f16)v0.z; o[3] = (f16)v0.w;
        o[4] = (f16)v1.x; o[5] = (f16)v1.y; o[6] = (f16)v1.z; o[7] = (f16)v1.w;
        *(f16x8*)(Ch + (size_t)orow * HIDDEN + c0 + i * 8) = o;
      }
    }
  } else {
    // readout: out[perm[m]] = relu(h2)[m,:] . Wr + br (reduce over r-lanes)
    float p[4] = {0.f, 0.f, 0.f, 0.f};
#pragma unroll
    for (int nf = 0; nf < 8; ++nf) {
      float bv = b2[nf * 16 + r];
      float wv = Wr[nf * 16 + r];
#pragma unroll
      for (int q = 0; q < 4; ++q) {
        float h = fmaxf(acc[nf][q] + bv, 0.f);
        p[q] += h * wv;
      }
    }
#pragma unroll
    for (int q = 0; q < 4; ++q) {
      p[q] += __shfl_xor(p[q], 8);
      p[q] += __shfl_xor(p[q], 4);
      p[q] += __shfl_xor(p[q], 2);
      p[q] += __shfl_xor(p[q], 1);
    }
    if (r == 0) {
      float brv = br[0];
#pragma unroll
      for (int q = 0; q < 4; ++q) {
        int gm = mBase + g * 4 + q;
        if (gm < M) outv[perm[gm]] = p[q] + brv;
      }
    }
  }
}

extern "C" void kernel_launch(void* const* d_in, const int* in_sizes, int n_in,
                              void* d_out, int out_size, void* d_ws,
                              size_t ws_size, hipStream_t stream) {
  const float* x = (const float*)d_in[0];
  const int* ei = (const int*)d_in[1];
  const float* W1_0 = (const float*)d_in[2];
  const float* b1_0 = (const float*)d_in[3];
  const float* W2_0 = (const float*)d_in[4];
  const float* b2_0 = (const float*)d_in[5];
  const float* W1_1 = (const float*)d_in[6];
  const float* b1_1 = (const float*)d_in[7];
  const float* W2_1 = (const float*)d_in[8];
  const float* b2_1 = (const float*)d_in[9];
  const float* Wr = (const float*)d_in[10];
  const float* br = (const float*)d_in[11];

  const int M = in_sizes[0] / HIDDEN;  // 50000 nodes
  const int E = in_sizes[1] / 2;       // 800000 edges
  const int* src = ei;
  const int* dst = ei + E;
  const int NB = (M + NPB - 1) >> NB_SHIFT;  // 391 buckets

  // workspace layout. pairs dies after build_csr; scratch region reused.
  int* pairs = (int*)d_ws;                   // [E] packed (dst&127)<<25|src
  f16* xh = (f16*)(pairs + E);               // [M,128] fp16 features
  f16* Bh = xh + (size_t)M * HIDDEN;         // [M,128] fp16 layer-0 hidden
  int* rowptr = (int*)(Bh + (size_t)M * HIDDEN); // [M+1]
  int* col = rowptr + M + 1;                 // [E]
  int* bcnt = col + E;                       // [512]
  int* pairOff = bcnt + 512;                 // [513]
  int* gCursor = pairOff + 513;              // [512]
  int* dhist = gCursor + 512;                // [256]
  int* dcur = dhist + 256;                   // [256]
  int* perm = dcur + 256;                    // [M]
  ushort* Wpk = (ushort*)(perm + M);         // 4 x (hi 32KB + lo 32KB)

  const int ginBlocks = (M + 63) / 64;
  const int cvtBlocks = (M * 16 + 255) / 256;  // M*128/8 threads
  const int edgeBlocks = (E + EPB - 1) / EPB;
  const int nodeBlocks = (M + 255) / 256;
  float* out = (float*)d_out;

  // ---- prepack weights + fp16 feature copy (independent of CSR chain)
  prepack_kernel<<<32, 256, 0, stream>>>(W1_0, W2_0, W1_1, W2_1, Wpk);
  f2h_kernel<<<cvtBlocks, 256, 0, stream>>>(x, xh, M * 16);

  // ---- build CSR via bucket sort
  hipMemsetAsync(bcnt, 0, 512 * sizeof(int), stream);
  hipMemsetAsync(dhist, 0, 256 * sizeof(int), stream);
  bucket_hist_kernel<<<edgeBlocks, 256, 0, stream>>>(dst, bcnt, E, NB);
  scan_buckets_kernel<<<1, 256, 0, stream>>>(bcnt, pairOff, gCursor, NB);
  partition_kernel<<<edgeBlocks, 256, 0, stream>>>(src, dst, gCursor, pairs,
                                                   E, NB);
  build_csr_kernel<<<NB, 256, 0, stream>>>(pairs, pairOff, rowptr, col, M, E,
                                           NB);

  // ---- degree counting-sort -> perm (descending degree, LPT scheduling)
  deg_hist_kernel<<<nodeBlocks, 256, 0, stream>>>(rowptr, dhist, M);
  deg_scan_kernel<<<1, 256, 0, stream>>>(dhist, dcur);
  deg_scatter_kernel<<<nodeBlocks, 256, 0, stream>>>(rowptr, dcur, perm, M);

  // ---- layer 0: fused gather+MLP (xh -> Bh fp16)
  gin_layer_kernel<<<ginBlocks, 256, 0, stream>>>(
      xh, rowptr, col, perm, Wpk, b1_0, Wpk + 32768, b2_0, Bh,
      nullptr, nullptr, nullptr, M, 0);

  // ---- layer 1: fused gather+MLP+readout (Bh -> out)
  gin_layer_kernel<<<ginBlocks, 256, 0, stream>>>(
      Bh, rowptr, col, perm, Wpk + 65536, b1_1, Wpk + 98304, b2_1, nullptr,
      Wr, br, out, M, 1);
}

// Round 9
// 254.658 us; speedup vs baseline: 1.5693x; 1.5693x over previous
//
#include <hip/hip_runtime.h>

#define HIDDEN 128
#define NB_SHIFT 7            // 128 dst nodes per bucket
#define NPB 128               // nodes per bucket
#define EPB 4096              // edges per partition/hist block

typedef __attribute__((ext_vector_type(8))) short short8;
typedef __attribute__((ext_vector_type(4))) float f32x4;
typedef _Float16 f16;
typedef __attribute__((ext_vector_type(8))) _Float16 f16x8;

// float -> bf16 (RNE), and back
__device__ __forceinline__ ushort f2bf(float a) {
  union { float f; unsigned u; } c; c.f = a;
  return (ushort)((c.u + 0x7FFFu + ((c.u >> 16) & 1u)) >> 16);
}
__device__ __forceinline__ float bf2f(ushort h) {
  union { unsigned u; float f; } c; c.u = ((unsigned)h) << 16;
  return c.f;
}

// ---------------------------------------------------------------------------
// CSR build A: per-bucket edge histogram (LDS-local, then merge).
// ---------------------------------------------------------------------------
__global__ __launch_bounds__(256) void bucket_hist_kernel(
    const int* __restrict__ dst, int* __restrict__ bcnt, int E, int NB) {
  __shared__ int loc[512];
  const int t = threadIdx.x;
  loc[t] = 0; loc[t + 256] = 0;
  __syncthreads();
  const int base = blockIdx.x * EPB;
  const int end = min(base + EPB, E);
  for (int e = base + t; e < end; e += 256)
    atomicAdd(&loc[dst[e] >> NB_SHIFT], 1);
  __syncthreads();
  for (int b = t; b < NB; b += 256)
    if (loc[b]) atomicAdd(&bcnt[b], loc[b]);
}

// ---------------------------------------------------------------------------
// CSR build B: exclusive scan of <=512 bucket counts -> pairOff + gCursor.
// ---------------------------------------------------------------------------
__global__ __launch_bounds__(256) void scan_buckets_kernel(
    const int* __restrict__ bcnt, int* __restrict__ pairOff,
    int* __restrict__ gCursor, int NB) {
  __shared__ int sh[512];
  const int t = threadIdx.x;
  const int v0 = (t < NB) ? bcnt[t] : 0;
  const int v1 = (t + 256 < NB) ? bcnt[t + 256] : 0;
  sh[t] = v0; sh[t + 256] = v1;
  __syncthreads();
#pragma unroll
  for (int off = 1; off < 512; off <<= 1) {
    int a = (t >= off) ? sh[t - off] : 0;
    int b = (t + 256 >= off) ? sh[t + 256 - off] : 0;
    __syncthreads();
    sh[t] += a; sh[t + 256] += b;
    __syncthreads();
  }
  const int e0 = sh[t] - v0;        // exclusive
  const int e1 = sh[t + 256] - v1;
  pairOff[t] = e0; gCursor[t] = e0;
  pairOff[t + 256] = e1; gCursor[t + 256] = e1;
  if (t == 255) pairOff[512] = sh[511];
}

// ---------------------------------------------------------------------------
// CSR build C: partition edges into bucket-contiguous PACKED pairs:
//   p = (dst & 127) << 25 | src      (src < 2^25)
// ---------------------------------------------------------------------------
__global__ __launch_bounds__(256) void partition_kernel(
    const int* __restrict__ src, const int* __restrict__ dst,
    int* __restrict__ gCursor, int* __restrict__ pairs, int E, int NB) {
  __shared__ int loc[512];
  __shared__ int cur[512];
  const int t = threadIdx.x;
  loc[t] = 0; loc[t + 256] = 0;
  __syncthreads();
  const int base = blockIdx.x * EPB;
  const int end = min(base + EPB, E);
  for (int e = base + t; e < end; e += 256)
    atomicAdd(&loc[dst[e] >> NB_SHIFT], 1);
  __syncthreads();
  for (int b = t; b < NB; b += 256)
    cur[b] = loc[b] ? atomicAdd(&gCursor[b], loc[b]) : 0;
  __syncthreads();
  for (int e = base + t; e < end; e += 256) {
    const int d = dst[e];
    const int p = atomicAdd(&cur[d >> NB_SHIFT], 1);
    pairs[p] = ((d & (NPB - 1)) << 25) | src[e];
  }
}

// ---------------------------------------------------------------------------
// CSR build D: one block per bucket -> rowptr + col (dense, L2-resident).
// ---------------------------------------------------------------------------
__global__ __launch_bounds__(256) void build_csr_kernel(
    const int* __restrict__ pairs, const int* __restrict__ pairOff,
    int* __restrict__ rowptr, int* __restrict__ col, int M, int E, int NB) {
  __shared__ int deg[NPB];
  __shared__ int pre[NPB];
  __shared__ int cur[NPB];
  const int b = blockIdx.x;
  const int t = threadIdx.x;
  const int s = pairOff[b];
  const int e2 = pairOff[b + 1];
  const int nodeBase = b << NB_SHIFT;
  const int nNodes = min(NPB, M - nodeBase);
  if (t < NPB) deg[t] = 0;
  __syncthreads();
  for (int i = s + t; i < e2; i += 256)
    atomicAdd(&deg[((unsigned)pairs[i]) >> 25], 1);
  __syncthreads();
  if (t < NPB) pre[t] = deg[t];
  __syncthreads();
#pragma unroll
  for (int off = 1; off < NPB; off <<= 1) {
    int v = (t < NPB && t >= off) ? pre[t - off] : 0;
    __syncthreads();
    if (t < NPB) pre[t] += v;
    __syncthreads();
  }
  if (t < nNodes) rowptr[nodeBase + t] = s + pre[t] - deg[t];
  if (b == NB - 1 && t == 0) rowptr[M] = E;
  if (t < NPB) cur[t] = pre[t] - deg[t];
  __syncthreads();
  for (int i = s + t; i < e2; i += 256) {
    const int pr = pairs[i];
    const int pos = s + atomicAdd(&cur[((unsigned)pr) >> 25], 1);
    col[pos] = pr & 0x1FFFFFF;
  }
}

// ---------------------------------------------------------------------------
// fp32 -> fp16 feature convert (8 elems/thread)
// ---------------------------------------------------------------------------
__global__ __launch_bounds__(256) void f2h_kernel(const float* __restrict__ in,
                                                  f16* __restrict__ out, int n8) {
  int i = blockIdx.x * 256 + threadIdx.x;
  if (i >= n8) return;
  const float4* p = (const float4*)(in + (size_t)i * 8);
  float4 a = p[0], b = p[1];
  f16x8 o;
  o[0] = (f16)a.x; o[1] = (f16)a.y; o[2] = (f16)a.z; o[3] = (f16)a.w;
  o[4] = (f16)b.x; o[5] = (f16)b.y; o[6] = (f16)b.z; o[7] = (f16)b.w;
  *(f16x8*)(out + (size_t)i * 8) = o;
}

// ---------------------------------------------------------------------------
// Prepack weights into MFMA B-fragment-linear bf16 hi/lo planes.
//   frag (ks, nf), lane, j  ->  k = ks*32 + (lane>>4)*8 + j, n = nf*16 + (lane&15)
// ---------------------------------------------------------------------------
__global__ __launch_bounds__(256) void prepack_kernel(
    const float* __restrict__ Wa, const float* __restrict__ Wb,
    const float* __restrict__ Wc, const float* __restrict__ Wd,
    ushort* __restrict__ out) {
  int idx = blockIdx.x * 256 + threadIdx.x;  // 0..8191
  int w = idx >> 11;
  int rem = idx & 2047;
  int ks = rem >> 9;
  int nf = (rem >> 6) & 7;
  int lane = rem & 63;
  const float* W = (w == 0) ? Wa : (w == 1) ? Wb : (w == 2) ? Wc : Wd;
  const int kbase = ks * 32 + (lane >> 4) * 8;
  const int n = nf * 16 + (lane & 15);
  ushort* oh = out + (size_t)w * 32768 + (size_t)rem * 8;
  ushort* ol = oh + 16384;
#pragma unroll
  for (int j = 0; j < 8; ++j) {
    float v = W[(size_t)(kbase + j) * HIDDEN + n];
    ushort h = f2bf(v);
    oh[j] = h;
    ol[j] = f2bf(v - bf2f(h));
  }
}

// ---------------------------------------------------------------------------
// FUSED GIN layer (R5 structure; degree-sort dropped — R8 showed ~0 gain).
// Block = 64 nodes, 4 waves x 16 nodes. Lane (r,g) owns node row r's dims
// {ks*32+g*8..+8} == the MFMA A-fragment decomposition: gather accumulators
// feed GEMM1 from registers, no global intermediate.
// R8 lesson: gather is LATENCY-bound (divergence fix gained 0; VALUBusy 18%,
// ~12 waves/CU). Fix here = deeper MLP: edge loop unrolled 2->4 (16 row
// loads + 4 col loads in flight per iteration, 2x the outstanding misses).
// h1 stride 133 (bank step 5, invertible mod 32): GEMM2 b128 A-reads and
// bias writes 2-way (free) vs 8-/4-way at 132. Zero __syncthreads.
// LDS 34 KB -> 4 blocks/CU; launch_bounds(256,4) caps VGPR at 128.
// ---------------------------------------------------------------------------
__global__ __launch_bounds__(256, 4) void gin_layer_kernel(
    const f16* __restrict__ xh, const int* __restrict__ rowptr,
    const int* __restrict__ col, const ushort* __restrict__ W1p,
    const float* __restrict__ b1, const ushort* __restrict__ W2p,
    const float* __restrict__ b2, f16* __restrict__ Ch,
    const float* __restrict__ Wr, const float* __restrict__ br,
    float* __restrict__ outv, int M, int doReadout) {
  __shared__ float h1[4][16][133];
  const int t = threadIdx.x;
  const int lane = t & 63;
  const int w = t >> 6;
  const int r = lane & 15;     // node row within wave / D col index
  const int g = lane >> 4;     // k-group / D row group
  const int mBase = blockIdx.x * 64 + w * 16;
  int arow = mBase + r;
  if (arow > M - 1) arow = M - 1;  // clamp: garbage only affects rows >= M

  // ---- fused aggregation: a32[ks][j] = xh[arow] + sum_e xh[col[e]]
  float a32[4][8];
  {
    const f16* rp = xh + (size_t)arow * HIDDEN + g * 8;
    f16x8 s0 = *(const f16x8*)(rp);
    f16x8 s1 = *(const f16x8*)(rp + 32);
    f16x8 s2 = *(const f16x8*)(rp + 64);
    f16x8 s3 = *(const f16x8*)(rp + 96);
#pragma unroll
    for (int j = 0; j < 8; ++j) {
      a32[0][j] = (float)s0[j]; a32[1][j] = (float)s1[j];
      a32[2][j] = (float)s2[j]; a32[3][j] = (float)s3[j];
    }
    const int s = rowptr[arow];
    const int e = rowptr[arow + 1];
    int i = s;
    // 4-edge unroll: 4 col loads + 16 row loads in flight per iteration
    for (; i + 3 < e; i += 4) {
      const int c0 = col[i], c1 = col[i + 1], c2 = col[i + 2], c3 = col[i + 3];
      const f16* p0 = xh + (size_t)c0 * HIDDEN + g * 8;
      const f16* p1 = xh + (size_t)c1 * HIDDEN + g * 8;
      const f16* p2 = xh + (size_t)c2 * HIDDEN + g * 8;
      const f16* p3 = xh + (size_t)c3 * HIDDEN + g * 8;
      f16x8 u0 = *(const f16x8*)(p0);
      f16x8 u1 = *(const f16x8*)(p0 + 32);
      f16x8 u2 = *(const f16x8*)(p0 + 64);
      f16x8 u3 = *(const f16x8*)(p0 + 96);
      f16x8 v0 = *(const f16x8*)(p1);
      f16x8 v1 = *(const f16x8*)(p1 + 32);
      f16x8 v2 = *(const f16x8*)(p1 + 64);
      f16x8 v3 = *(const f16x8*)(p1 + 96);
      f16x8 w0 = *(const f16x8*)(p2);
      f16x8 w1 = *(const f16x8*)(p2 + 32);
      f16x8 w2 = *(const f16x8*)(p2 + 64);
      f16x8 w3 = *(const f16x8*)(p2 + 96);
      f16x8 x0 = *(const f16x8*)(p3);
      f16x8 x1 = *(const f16x8*)(p3 + 32);
      f16x8 x2 = *(const f16x8*)(p3 + 64);
      f16x8 x3 = *(const f16x8*)(p3 + 96);
#pragma unroll
      for (int j = 0; j < 8; ++j) {
        a32[0][j] += ((float)u0[j] + (float)v0[j]) + ((float)w0[j] + (float)x0[j]);
        a32[1][j] += ((float)u1[j] + (float)v1[j]) + ((float)w1[j] + (float)x1[j]);
        a32[2][j] += ((float)u2[j] + (float)v2[j]) + ((float)w2[j] + (float)x2[j]);
        a32[3][j] += ((float)u3[j] + (float)v3[j]) + ((float)w3[j] + (float)x3[j]);
      }
    }
    for (; i < e; ++i) {
      const int c0 = col[i];
      const f16* p0 = xh + (size_t)c0 * HIDDEN + g * 8;
      f16x8 u0 = *(const f16x8*)(p0);
      f16x8 u1 = *(const f16x8*)(p0 + 32);
      f16x8 u2 = *(const f16x8*)(p0 + 64);
      f16x8 u3 = *(const f16x8*)(p0 + 96);
#pragma unroll
      for (int j = 0; j < 8; ++j) {
        a32[0][j] += (float)u0[j];
        a32[1][j] += (float)u1[j];
        a32[2][j] += (float)u2[j];
        a32[3][j] += (float)u3[j];
      }
    }
  }

  f32x4 acc[8];
#pragma unroll
  for (int i = 0; i < 8; ++i) acc[i] = (f32x4){0.f, 0.f, 0.f, 0.f};

  // ---- GEMM1: acc[nf] += a32(16x128) @ W1[:, nf*16..]
#pragma unroll
  for (int ks = 0; ks < 4; ++ks) {
    short8 ah, al;
#pragma unroll
    for (int j = 0; j < 8; ++j) {
      ushort h = f2bf(a32[ks][j]);
      ah[j] = (short)h;
      al[j] = (short)f2bf(a32[ks][j] - bf2f(h));
    }
#pragma unroll
    for (int nf = 0; nf < 8; ++nf) {
      const ushort* bp = W1p + ((size_t)(ks * 8 + nf) * 64 + lane) * 8;
      short8 bh = *(const short8*)bp;
      short8 bl = *(const short8*)(bp + 16384);
      acc[nf] = __builtin_amdgcn_mfma_f32_16x16x32_bf16(ah, bh, acc[nf], 0, 0, 0);
      acc[nf] = __builtin_amdgcn_mfma_f32_16x16x32_bf16(al, bh, acc[nf], 0, 0, 0);
      acc[nf] = __builtin_amdgcn_mfma_f32_16x16x32_bf16(ah, bl, acc[nf], 0, 0, 0);
    }
  }

  // ---- bias + relu, park h1 in wave-private LDS (row=4g+q, col=nf*16+r)
#pragma unroll
  for (int nf = 0; nf < 8; ++nf) {
    float bv = b1[nf * 16 + r];
#pragma unroll
    for (int q = 0; q < 4; ++q)
      h1[w][g * 4 + q][nf * 16 + r] = fmaxf(acc[nf][q] + bv, 0.f);
    acc[nf] = (f32x4){0.f, 0.f, 0.f, 0.f};
  }

  // ---- GEMM2: acc[nf] += h1(16x128) @ W2[:, nf*16..] (A-frags from LDS)
#pragma unroll
  for (int ks = 0; ks < 4; ++ks) {
    const float* hp = &h1[w][r][ks * 32 + g * 8];
    float4 a0 = *(const float4*)hp;
    float4 a1 = *(const float4*)(hp + 4);
    float av[8] = {a0.x, a0.y, a0.z, a0.w, a1.x, a1.y, a1.z, a1.w};
    short8 ah, al;
#pragma unroll
    for (int j = 0; j < 8; ++j) {
      ushort h = f2bf(av[j]);
      ah[j] = (short)h;
      al[j] = (short)f2bf(av[j] - bf2f(h));
    }
#pragma unroll
    for (int nf = 0; nf < 8; ++nf) {
      const ushort* bp = W2p + ((size_t)(ks * 8 + nf) * 64 + lane) * 8;
      short8 bh = *(const short8*)bp;
      short8 bl = *(const short8*)(bp + 16384);
      acc[nf] = __builtin_amdgcn_mfma_f32_16x16x32_bf16(ah, bh, acc[nf], 0, 0, 0);
      acc[nf] = __builtin_amdgcn_mfma_f32_16x16x32_bf16(al, bh, acc[nf], 0, 0, 0);
      acc[nf] = __builtin_amdgcn_mfma_f32_16x16x32_bf16(ah, bl, acc[nf], 0, 0, 0);
    }
  }

  if (!doReadout) {
    // bias + relu -> LDS, then coalesced fp16 stores
#pragma unroll
    for (int nf = 0; nf < 8; ++nf) {
      float bv = b2[nf * 16 + r];
#pragma unroll
      for (int q = 0; q < 4; ++q)
        h1[w][g * 4 + q][nf * 16 + r] = fmaxf(acc[nf][q] + bv, 0.f);
    }
    const int rr = lane >> 2;          // 0..15
    const int c0 = (lane & 3) * 32;    // 0,32,64,96
    const int gm = mBase + rr;
    if (gm < M) {
#pragma unroll
      for (int i = 0; i < 4; ++i) {
        float4 v0 = *(const float4*)&h1[w][rr][c0 + i * 8];
        float4 v1 = *(const float4*)&h1[w][rr][c0 + i * 8 + 4];
        f16x8 o;
        o[0] = (f16)v0.x; o[1] = (f16)v0.y; o[2] = (f16)v0.z; o[3] = (f16)v0.w;
        o[4] = (f16)v1.x; o[5] = (f16)v1.y; o[6] = (f16)v1.z; o[7] = (f16)v1.w;
        *(f16x8*)(Ch + (size_t)gm * HIDDEN + c0 + i * 8) = o;
      }
    }
  } else {
    // readout: out[m] = relu(h2)[m,:] . Wr + br, reduced across 16 r-lanes
    float p[4] = {0.f, 0.f, 0.f, 0.f};
#pragma unroll
    for (int nf = 0; nf < 8; ++nf) {
      float bv = b2[nf * 16 + r];
      float wv = Wr[nf * 16 + r];
#pragma unroll
      for (int q = 0; q < 4; ++q) {
        float h = fmaxf(acc[nf][q] + bv, 0.f);
        p[q] += h * wv;
      }
    }
#pragma unroll
    for (int q = 0; q < 4; ++q) {
      p[q] += __shfl_xor(p[q], 8);
      p[q] += __shfl_xor(p[q], 4);
      p[q] += __shfl_xor(p[q], 2);
      p[q] += __shfl_xor(p[q], 1);
    }
    if (r == 0) {
      float brv = br[0];
#pragma unroll
      for (int q = 0; q < 4; ++q) {
        int gm = mBase + g * 4 + q;
        if (gm < M) outv[gm] = p[q] + brv;
      }
    }
  }
}

extern "C" void kernel_launch(void* const* d_in, const int* in_sizes, int n_in,
                              void* d_out, int out_size, void* d_ws,
                              size_t ws_size, hipStream_t stream) {
  const float* x = (const float*)d_in[0];
  const int* ei = (const int*)d_in[1];
  const float* W1_0 = (const float*)d_in[2];
  const float* b1_0 = (const float*)d_in[3];
  const float* W2_0 = (const float*)d_in[4];
  const float* b2_0 = (const float*)d_in[5];
  const float* W1_1 = (const float*)d_in[6];
  const float* b1_1 = (const float*)d_in[7];
  const float* W2_1 = (const float*)d_in[8];
  const float* b2_1 = (const float*)d_in[9];
  const float* Wr = (const float*)d_in[10];
  const float* br = (const float*)d_in[11];

  const int M = in_sizes[0] / HIDDEN;  // 50000 nodes
  const int E = in_sizes[1] / 2;       // 800000 edges
  const int* src = ei;
  const int* dst = ei + E;
  const int NB = (M + NPB - 1) >> NB_SHIFT;  // 391 buckets

  // workspace layout. pairs dies after build_csr; scratch region reused.
  int* pairs = (int*)d_ws;                   // [E] packed (dst&127)<<25|src
  f16* xh = (f16*)(pairs + E);               // [M,128] fp16 features
  f16* Bh = xh + (size_t)M * HIDDEN;         // [M,128] fp16 layer-0 hidden
  int* rowptr = (int*)(Bh + (size_t)M * HIDDEN); // [M+1]
  int* col = rowptr + M + 1;                 // [E]
  int* bcnt = col + E;                       // [512]
  int* pairOff = bcnt + 512;                 // [513]
  int* gCursor = pairOff + 513;              // [512]
  ushort* Wpk = (ushort*)(gCursor + 512);    // 4 x (hi 32KB + lo 32KB)

  const int ginBlocks = (M + 63) / 64;
  const int cvtBlocks = (M * 16 + 255) / 256;  // M*128/8 threads
  const int edgeBlocks = (E + EPB - 1) / EPB;
  float* out = (float*)d_out;

  // ---- prepack weights + fp16 feature copy (independent of CSR chain)
  prepack_kernel<<<32, 256, 0, stream>>>(W1_0, W2_0, W1_1, W2_1, Wpk);
  f2h_kernel<<<cvtBlocks, 256, 0, stream>>>(x, xh, M * 16);

  // ---- build CSR via bucket sort
  hipMemsetAsync(bcnt, 0, 512 * sizeof(int), stream);
  bucket_hist_kernel<<<edgeBlocks, 256, 0, stream>>>(dst, bcnt, E, NB);
  scan_buckets_kernel<<<1, 256, 0, stream>>>(bcnt, pairOff, gCursor, NB);
  partition_kernel<<<edgeBlocks, 256, 0, stream>>>(src, dst, gCursor, pairs,
                                                   E, NB);
  build_csr_kernel<<<NB, 256, 0, stream>>>(pairs, pairOff, rowptr, col, M, E,
                                           NB);

  // ---- layer 0: fused gather+MLP (xh -> Bh fp16)
  gin_layer_kernel<<<ginBlocks, 256, 0, stream>>>(
      xh, rowptr, col, Wpk, b1_0, Wpk + 32768, b2_0, Bh,
      nullptr, nullptr, nullptr, M, 0);

  // ---- layer 1: fused gather+MLP+readout (Bh -> out)
  gin_layer_kernel<<<ginBlocks, 256, 0, stream>>>(
      Bh, rowptr, col, Wpk + 65536, b1_1, Wpk + 98304, b2_1, nullptr,
      Wr, br, out, M, 1);
}